// Round 12
// baseline (43.550 us; speedup 1.0000x reference)
//
#include <hip/hip_runtime.h>
#include <hip/hip_bf16.h>

typedef __attribute__((ext_vector_type(8))) short short8;
typedef __attribute__((ext_vector_type(4))) float floatx4;

#define D_DIM 128
#define SCALE_F 1.6986436f          /* sqrt(2*log2(e)); (s*a)·(s*b) = 2*log2(e)*a·b */
#define CS 16                        /* column chunks (grid.y) */
#define CTILE 64                     /* columns staged per LDS tile */
#define BLK_ROWS 256                 /* rows per block (4 M-waves x 64 rows) */
#define MREP 4                       /* 16-row MFMA blocks per wave */

typedef __attribute__((address_space(1))) const unsigned int GUI;
typedef __attribute__((address_space(3))) unsigned int LUI;
#define GLOAD16(g, l) __builtin_amdgcn_global_load_lds((GUI*)(g), (LUI*)(l), 16, 0, 0)

// ---- prep: normalize rows, scale by sqrt(2log2e) -> bf16 Z; fp32 pos dots; bf16 self-dots ----
__global__ void prep_kernel(const float* __restrict__ zi,
                            const float* __restrict__ zj,
                            __hip_bfloat16* __restrict__ Zb,
                            float* __restrict__ posdot,
                            float* __restrict__ selfarg, int N) {
    int r = blockIdx.x * 4 + (threadIdx.x >> 6);   // 4 rows per 256-thread block
    int t = threadIdx.x & 63;
    const float* pi = zi + (size_t)r * D_DIM;
    const float* pj = zj + (size_t)r * D_DIM;
    float a0 = pi[t], a1 = pi[t + 64];
    float b0 = pj[t], b1 = pj[t + 64];
    float ssi = a0*a0 + a1*a1;
    float ssj = b0*b0 + b1*b1;
    float sij = a0*b0 + a1*b1;
#pragma unroll
    for (int off = 1; off < 64; off <<= 1) {
        ssi += __shfl_xor(ssi, off);
        ssj += __shfl_xor(ssj, off);
        sij += __shfl_xor(sij, off);
    }
    float ni = sqrtf(ssi), nj = sqrtf(ssj);
    float ri = SCALE_F / ni, rj = SCALE_F / nj;
    __hip_bfloat16 vi0 = __float2bfloat16(a0 * ri);
    __hip_bfloat16 vi1 = __float2bfloat16(a1 * ri);
    __hip_bfloat16 vj0 = __float2bfloat16(b0 * rj);
    __hip_bfloat16 vj1 = __float2bfloat16(b1 * rj);
    __hip_bfloat16* zr0 = Zb + (size_t)r * D_DIM;
    __hip_bfloat16* zr1 = Zb + (size_t)(r + N) * D_DIM;
    zr0[t]      = vi0;  zr0[t + 64] = vi1;
    zr1[t]      = vj0;  zr1[t + 64] = vj1;
    float fi0 = __bfloat162float(vi0), fi1 = __bfloat162float(vi1);
    float fj0 = __bfloat162float(vj0), fj1 = __bfloat162float(vj1);
    float sdi = fi0*fi0 + fi1*fi1;
    float sdj = fj0*fj0 + fj1*fj1;
#pragma unroll
    for (int off = 1; off < 64; off <<= 1) {
        sdi += __shfl_xor(sdi, off);
        sdj += __shfl_xor(sdj, off);
    }
    if (t == 0) {
        posdot[r] = sij / fmaxf(ni * nj, 1e-8f);
        selfarg[r]     = sdi;
        selfarg[r + N] = sdj;
    }
}

// ---- main: fused Gram x exp2 x rowsum ----
// grid (32, CS); 512 threads = 8 waves: 4 in M (64 rows each) x 2 in N (32-col halves).
// A: 64 VGPRs resident (pinned ONCE, pre-loop). B: double-buffered LDS via
// global_load_lds (linear dest, pre-swizzled source; reads use same XOR involution).
// (512,2): no forced 128-VGPR cap -> no spill; worst case 1 block/CU.
__global__ __launch_bounds__(512, 2)
void main_kernel(const ushort* __restrict__ Zu,
                 float* __restrict__ rowpart, int N2) {
    __shared__ ushort Btile[2][CTILE * D_DIM];   // 2 x 16 KB

    const int tid  = threadIdx.x;
    const int lane = tid & 63;
    const int wave = tid >> 6;      // 0..7
    const int mw   = wave & 3;      // M-wave: which 64-row group
    const int nh   = wave >> 2;     // N-half: which 32 cols of the tile
    const int m    = lane & 15;
    const int kg   = lane >> 4;
    const int rwave0 = blockIdx.x * BLK_ROWS + mw * 64;
    const int cy   = blockIdx.y;

    const int cols_per_chunk = N2 / CS;          // 512
    const int ntile = cols_per_chunk / CTILE;    // 8
    const int c0base = cy * cols_per_chunk;

    // staging coords: thread handles 16B chunks (tid) and (512+tid) of a 16 KB tile.
    // LDS dest LINEAR; global source slot XOR-pre-swizzled.
    const int srow0 = tid >> 4,        sslot0 = (tid & 15) ^ (srow0 & 7);
    const int srow1 = 32 + (tid >> 4), sslot1 = (tid & 15) ^ (srow1 & 7);
    const ushort* gsrc0 = Zu + (size_t)(c0base + srow0) * D_DIM + sslot0 * 8;
    const ushort* gsrc1 = Zu + (size_t)(c0base + srow1) * D_DIM + sslot1 * 8;
    const size_t tadv = (size_t)CTILE * D_DIM;   // elements per tile step

    // issue tile-0 DMA FIRST so its latency overlaps the A-fragment loads
    GLOAD16(gsrc0, &Btile[0][(size_t)tid * 8]);
    GLOAD16(gsrc1, &Btile[0][(size_t)(512 + tid) * 8]);

    // A fragments: 4 row-blocks x 4 k-steps = 64 VGPRs, loaded once from global.
    short8 afrag[MREP][4];
#pragma unroll
    for (int rb = 0; rb < MREP; ++rb) {
        const ushort* ap = Zu + (size_t)(rwave0 + rb * 16 + m) * D_DIM + kg * 8;
#pragma unroll
        for (int ks = 0; ks < 4; ++ks)
            afrag[rb][ks] = *(const short8*)(ap + ks * 32);
    }
    // pin once: opaque redefinition blocks remat/sinking for the whole loop (R9-neutral)
#pragma unroll
    for (int rb = 0; rb < MREP; ++rb)
#pragma unroll
        for (int ks = 0; ks < 4; ++ks)
            asm volatile("" : "+v"(afrag[rb][ks]));

    float rowacc[MREP][4];
#pragma unroll
    for (int rb = 0; rb < MREP; ++rb)
#pragma unroll
        for (int g = 0; g < 4; ++g) rowacc[rb][g] = 0.0f;

    __syncthreads();   // implicit vmcnt(0) drain covers tile-0 DMA + afrag loads

    for (int t = 0; t < ntile; ++t) {
        // issue next tile's DMA into the other buffer (no staging registers)
        if (t + 1 < ntile) {
            ushort* nbuf = Btile[(t + 1) & 1];
            GLOAD16(gsrc0 + (size_t)(t + 1) * tadv, &nbuf[(size_t)tid * 8]);
            GLOAD16(gsrc1 + (size_t)(t + 1) * tadv, &nbuf[(size_t)(512 + tid) * 8]);
        }

        const ushort* buf = Btile[t & 1];
#pragma unroll
        for (int s2 = 0; s2 < 2; ++s2) {
            const int brow = nh * 32 + s2 * 16 + m;
            short8 bfrag[4];
#pragma unroll
            for (int ks = 0; ks < 4; ++ks) {
                int ss = (ks * 4 + kg) ^ (brow & 7);
                bfrag[ks] = *(const short8*)&buf[brow * D_DIM + ss * 8];
            }
#pragma unroll
            for (int rb = 0; rb < MREP; ++rb) {
                // two independent 2-deep MFMA chains, merged before exp
                floatx4 ac0 = {0.f, 0.f, 0.f, 0.f};
                floatx4 ac1 = {0.f, 0.f, 0.f, 0.f};
                ac0 = __builtin_amdgcn_mfma_f32_16x16x32_bf16(afrag[rb][0], bfrag[0], ac0, 0, 0, 0);
                ac1 = __builtin_amdgcn_mfma_f32_16x16x32_bf16(afrag[rb][2], bfrag[2], ac1, 0, 0, 0);
                ac0 = __builtin_amdgcn_mfma_f32_16x16x32_bf16(afrag[rb][1], bfrag[1], ac0, 0, 0, 0);
                ac1 = __builtin_amdgcn_mfma_f32_16x16x32_bf16(afrag[rb][3], bfrag[3], ac1, 0, 0, 0);
#pragma unroll
                for (int g = 0; g < 4; ++g)
                    rowacc[rb][g] += __builtin_amdgcn_exp2f(ac0[g] + ac1[g]);
            }
        }
        __syncthreads();   // waves done reading buf[t&1]; next-tile DMA drained
    }

    // reduce across the 16 column lanes; each (cy, nh) writes its own partial slot
#pragma unroll
    for (int rb = 0; rb < MREP; ++rb)
#pragma unroll
        for (int g = 0; g < 4; ++g) {
            float v = rowacc[rb][g];
            v += __shfl_xor(v, 1);
            v += __shfl_xor(v, 2);
            v += __shfl_xor(v, 4);
            v += __shfl_xor(v, 8);
            if (m == 0) {
                int grow = rwave0 + rb * 16 + kg * 4 + g;
                rowpart[(size_t)(cy * 2 + nh) * N2 + grow] = v;
            }
        }
}

// ---- finalize stage 1: per-row loss, 32-block partial sums ----
__global__ void finalize1_kernel(const float* __restrict__ rowpart,
                                 const float* __restrict__ selfarg,
                                 const float* __restrict__ posdot,
                                 float* __restrict__ bpart, int N2, int NP) {
    __shared__ float red[4];
    int tid = threadIdx.x;                       // 0..255
    int r = blockIdx.x * 256 + tid;              // one row per thread
    float d0 = 0.f, d1 = 0.f, d2 = 0.f, d3 = 0.f;
#pragma unroll
    for (int q = 0; q < 2 * CS; q += 4) {
        d0 += rowpart[(size_t)(q + 0) * N2 + r];
        d1 += rowpart[(size_t)(q + 1) * N2 + r];
        d2 += rowpart[(size_t)(q + 2) * N2 + r];
        d3 += rowpart[(size_t)(q + 3) * N2 + r];
    }
    float denom = (d0 + d1) + (d2 + d3);
    denom -= __builtin_amdgcn_exp2f(selfarg[r]); // remove diagonal term
    float pos = posdot[r < NP ? r : r - NP];
    float v = logf(denom) - 2.0f * pos;          // -log(num/denom), 1/t = 2
#pragma unroll
    for (int off = 1; off < 64; off <<= 1) v += __shfl_xor(v, off);
    if ((tid & 63) == 0) red[tid >> 6] = v;
    __syncthreads();
    if (tid == 0) bpart[blockIdx.x] = red[0] + red[1] + red[2] + red[3];
}

// ---- finalize stage 2: mean ----
__global__ void finalize2_kernel(const float* __restrict__ bpart,
                                 float* __restrict__ out, int nb, int N2) {
    int t = threadIdx.x;  // 64
    float v = (t < nb) ? bpart[t] : 0.0f;
#pragma unroll
    for (int off = 1; off < 64; off <<= 1) v += __shfl_xor(v, off);
    if (t == 0) out[0] = v / (float)N2;
}

extern "C" void kernel_launch(void* const* d_in, const int* in_sizes, int n_in,
                              void* d_out, int out_size, void* d_ws, size_t ws_size,
                              hipStream_t stream) {
    const float* zi = (const float*)d_in[0];
    const float* zj = (const float*)d_in[1];
    const int N  = in_sizes[0] / D_DIM;   // 4096
    const int N2 = 2 * N;                 // 8192

    char* w = (char*)d_ws;
    __hip_bfloat16* Zb = (__hip_bfloat16*)w;
    size_t off = (size_t)N2 * D_DIM * sizeof(__hip_bfloat16);        // 2 MB
    float* posdot  = (float*)(w + off);  off += (size_t)N  * sizeof(float);
    float* selfarg = (float*)(w + off);  off += (size_t)N2 * sizeof(float);
    float* rowpart = (float*)(w + off);  off += (size_t)(2 * CS) * N2 * sizeof(float); // 1 MB
    float* bpart   = (float*)(w + off);

    prep_kernel<<<N / 4, 256, 0, stream>>>(zi, zj, Zb, posdot, selfarg, N);
    dim3 grid(N2 / BLK_ROWS, CS);
    main_kernel<<<grid, 512, 0, stream>>>((const ushort*)Zb, rowpart, N2);
    const int nb = N2 / 256;  // 32
    finalize1_kernel<<<nb, 256, 0, stream>>>(rowpart, selfarg, posdot, bpart, N2, N);
    finalize2_kernel<<<1, 64, 0, stream>>>(bpart, (float*)d_out, nb, N2);
}

// Round 13
// 32.030 us; speedup vs baseline: 1.3597x; 1.3597x over previous
//
#include <hip/hip_runtime.h>
#include <hip/hip_bf16.h>

typedef __attribute__((ext_vector_type(2))) long vlong2;
typedef __attribute__((ext_vector_type(4))) float floatx4;

#define D_DIM 128
#define SCALE_F 1.6986436f          /* sqrt(2*log2(e)); (s*a)·(s*b) = 2*log2(e)*a·b */
#define CS 16                        /* column chunks (grid.y) */
#define CTILE 64                     /* columns staged per LDS tile (8 KB in fp8) */
#define BLK_ROWS 256                 /* rows per block (4 M-waves x 64 rows) */
#define MREP 4                       /* 16-row MFMA blocks per wave */

typedef __attribute__((address_space(1))) const unsigned int GUI;
typedef __attribute__((address_space(3))) unsigned int LUI;
#define GLOAD16(g, l) __builtin_amdgcn_global_load_lds((GUI*)(g), (LUI*)(l), 16, 0, 0)

// ---- prep: normalize+scale rows -> fp8 e4m3 Z; fp32 pos dots; fp32 self-dots of rounded rows ----
__global__ void prep_kernel(const float* __restrict__ zi,
                            const float* __restrict__ zj,
                            unsigned char* __restrict__ Z8,
                            float* __restrict__ posdot,
                            float* __restrict__ selfarg, int N) {
    int r = blockIdx.x * 4 + (threadIdx.x >> 6);   // 4 rows per 256-thread block
    int t = threadIdx.x & 63;                      // handles elements 2t, 2t+1
    const float* pi = zi + (size_t)r * D_DIM;
    const float* pj = zj + (size_t)r * D_DIM;
    float a0 = pi[2 * t], a1 = pi[2 * t + 1];
    float b0 = pj[2 * t], b1 = pj[2 * t + 1];
    float ssi = a0*a0 + a1*a1;
    float ssj = b0*b0 + b1*b1;
    float sij = a0*b0 + a1*b1;
#pragma unroll
    for (int off = 1; off < 64; off <<= 1) {
        ssi += __shfl_xor(ssi, off);
        ssj += __shfl_xor(ssj, off);
        sij += __shfl_xor(sij, off);
    }
    float ni = sqrtf(ssi), nj = sqrtf(ssj);
    float ri = SCALE_F / ni, rj = SCALE_F / nj;
    int ui = __builtin_amdgcn_cvt_pk_fp8_f32(a0 * ri, a1 * ri, 0, false);
    int uj = __builtin_amdgcn_cvt_pk_fp8_f32(b0 * rj, b1 * rj, 0, false);
    *(ushort*)&Z8[(size_t)r * D_DIM + 2 * t]       = (ushort)(ui & 0xffff);
    *(ushort*)&Z8[(size_t)(r + N) * D_DIM + 2 * t] = (ushort)(uj & 0xffff);
    // self-dot of the fp8-rounded scaled rows (matches the fp8 Gram diagonal)
    float fi0 = __builtin_amdgcn_cvt_f32_fp8(ui, 0);
    float fi1 = __builtin_amdgcn_cvt_f32_fp8(ui, 1);
    float fj0 = __builtin_amdgcn_cvt_f32_fp8(uj, 0);
    float fj1 = __builtin_amdgcn_cvt_f32_fp8(uj, 1);
    float sdi = fi0*fi0 + fi1*fi1;
    float sdj = fj0*fj0 + fj1*fj1;
#pragma unroll
    for (int off = 1; off < 64; off <<= 1) {
        sdi += __shfl_xor(sdi, off);
        sdj += __shfl_xor(sdj, off);
    }
    if (t == 0) {
        posdot[r] = sij / fmaxf(ni * nj, 1e-8f);
        selfarg[r]     = sdi;
        selfarg[r + N] = sdj;
    }
}

// ---- main: fused fp8 Gram x exp2 x rowsum ----
// grid (32, CS); 512 threads = 8 waves: 4 in M (64 rows each) x 2 in N (32-col halves).
// A: 32 VGPRs resident (fp8, 64 rows x k128). B: dbuf LDS (2 x 8 KB) via global_load_lds.
// k-chunk assignment: MFMA (q,h) covers k = kg*32 + q*16 + h*8 (+0..7), so each lane's
// 16B LDS unit is 16 CONTIGUOUS global bytes; 16B-slot XOR-involution on both sides.
__global__ __launch_bounds__(512, 4)
void main_kernel(const unsigned char* __restrict__ Z8,
                 float* __restrict__ rowpart, int N2) {
    __shared__ unsigned char Btile[2][CTILE * D_DIM];   // 2 x 8 KB (fp8)

    const int tid  = threadIdx.x;
    const int lane = tid & 63;
    const int wave = tid >> 6;      // 0..7
    const int mw   = wave & 3;      // M-wave: which 64-row group
    const int nh   = wave >> 2;     // N-half: which 32 cols of the tile
    const int m    = lane & 15;
    const int kg   = lane >> 4;
    const int rwave0 = blockIdx.x * BLK_ROWS + mw * 64;
    const int cy   = blockIdx.y;

    const int cols_per_chunk = N2 / CS;          // 512
    const int ntile = cols_per_chunk / CTILE;    // 8
    const int c0base = cy * cols_per_chunk;

    // staging: thread handles 16B chunk tid of the 8 KB tile.
    // chunk -> (col = tid>>3, u = tid&7); v = u ^ (col&7); kg=v>>1, q=v&1;
    // source bytes = row(c0+col)*128 + kg*32 + q*16  (16 contiguous bytes).
    const int scol = tid >> 3;
    const int sv   = (tid & 7) ^ (scol & 7);
    const unsigned char* gsrc = Z8 + (size_t)(c0base + scol) * D_DIM
                                   + (sv >> 1) * 32 + (sv & 1) * 16;
    const size_t tadv = (size_t)CTILE * D_DIM;   // bytes per tile step

    // issue tile-0 DMA FIRST so its latency overlaps the A-fragment loads
    GLOAD16(gsrc, &Btile[0][(size_t)tid * 16]);

    // A fragments: 4 row-blocks x 2 q-pairs x 16B = 32 VGPRs, loaded once.
    vlong2 afrag[MREP][2];
#pragma unroll
    for (int rb = 0; rb < MREP; ++rb) {
        const unsigned char* ap = Z8 + (size_t)(rwave0 + rb * 16 + m) * D_DIM + kg * 32;
        afrag[rb][0] = *(const vlong2*)(ap);
        afrag[rb][1] = *(const vlong2*)(ap + 16);
    }
    // pin once: opaque redefinition blocks remat/sinking for the whole loop
#pragma unroll
    for (int rb = 0; rb < MREP; ++rb) {
        asm volatile("" : "+v"(afrag[rb][0]));
        asm volatile("" : "+v"(afrag[rb][1]));
    }

    float rowacc[MREP][4];
#pragma unroll
    for (int rb = 0; rb < MREP; ++rb)
#pragma unroll
        for (int g = 0; g < 4; ++g) rowacc[rb][g] = 0.0f;

    __syncthreads();   // implicit vmcnt(0) drain covers tile-0 DMA + afrag loads

    for (int t = 0; t < ntile; ++t) {
        if (t + 1 < ntile)
            GLOAD16(gsrc + (size_t)(t + 1) * tadv,
                    &Btile[(t + 1) & 1][(size_t)tid * 16]);

        const unsigned char* buf = Btile[t & 1];
#pragma unroll
        for (int s2 = 0; s2 < 2; ++s2) {
            const int bcol = nh * 32 + s2 * 16 + m;
            const int cb   = bcol * D_DIM;
            vlong2 bq0 = *(const vlong2*)&buf[cb + (((kg * 2 + 0) ^ (bcol & 7)) * 16)];
            vlong2 bq1 = *(const vlong2*)&buf[cb + (((kg * 2 + 1) ^ (bcol & 7)) * 16)];
#pragma unroll
            for (int rb = 0; rb < MREP; ++rb) {
                // two independent 2-deep MFMA chains, merged before exp
                floatx4 ac0 = {0.f, 0.f, 0.f, 0.f};
                floatx4 ac1 = {0.f, 0.f, 0.f, 0.f};
                ac0 = __builtin_amdgcn_mfma_f32_16x16x32_fp8_fp8(afrag[rb][0].x, bq0.x, ac0, 0, 0, 0);
                ac1 = __builtin_amdgcn_mfma_f32_16x16x32_fp8_fp8(afrag[rb][1].x, bq1.x, ac1, 0, 0, 0);
                ac0 = __builtin_amdgcn_mfma_f32_16x16x32_fp8_fp8(afrag[rb][0].y, bq0.y, ac0, 0, 0, 0);
                ac1 = __builtin_amdgcn_mfma_f32_16x16x32_fp8_fp8(afrag[rb][1].y, bq1.y, ac1, 0, 0, 0);
#pragma unroll
                for (int g = 0; g < 4; ++g)
                    rowacc[rb][g] += __builtin_amdgcn_exp2f(ac0[g] + ac1[g]);
            }
        }
        __syncthreads();   // waves done reading buf[t&1]; next-tile DMA drained
    }

    // reduce across the 16 column lanes; each (cy, nh) writes its own partial slot
#pragma unroll
    for (int rb = 0; rb < MREP; ++rb)
#pragma unroll
        for (int g = 0; g < 4; ++g) {
            float v = rowacc[rb][g];
            v += __shfl_xor(v, 1);
            v += __shfl_xor(v, 2);
            v += __shfl_xor(v, 4);
            v += __shfl_xor(v, 8);
            if (m == 0) {
                int grow = rwave0 + rb * 16 + kg * 4 + g;
                rowpart[(size_t)(cy * 2 + nh) * N2 + grow] = v;
            }
        }
}

// ---- finalize stage 1: per-row loss, 32-block partial sums ----
__global__ void finalize1_kernel(const float* __restrict__ rowpart,
                                 const float* __restrict__ selfarg,
                                 const float* __restrict__ posdot,
                                 float* __restrict__ bpart, int N2, int NP) {
    __shared__ float red[4];
    int tid = threadIdx.x;                       // 0..255
    int r = blockIdx.x * 256 + tid;              // one row per thread
    float d0 = 0.f, d1 = 0.f, d2 = 0.f, d3 = 0.f;
#pragma unroll
    for (int q = 0; q < 2 * CS; q += 4) {
        d0 += rowpart[(size_t)(q + 0) * N2 + r];
        d1 += rowpart[(size_t)(q + 1) * N2 + r];
        d2 += rowpart[(size_t)(q + 2) * N2 + r];
        d3 += rowpart[(size_t)(q + 3) * N2 + r];
    }
    float denom = (d0 + d1) + (d2 + d3);
    denom -= __builtin_amdgcn_exp2f(selfarg[r]); // remove diagonal term
    float pos = posdot[r < NP ? r : r - NP];
    float v = logf(denom) - 2.0f * pos;          // -log(num/denom), 1/t = 2
#pragma unroll
    for (int off = 1; off < 64; off <<= 1) v += __shfl_xor(v, off);
    if ((tid & 63) == 0) red[tid >> 6] = v;
    __syncthreads();
    if (tid == 0) bpart[blockIdx.x] = red[0] + red[1] + red[2] + red[3];
}

// ---- finalize stage 2: mean ----
__global__ void finalize2_kernel(const float* __restrict__ bpart,
                                 float* __restrict__ out, int nb, int N2) {
    int t = threadIdx.x;  // 64
    float v = (t < nb) ? bpart[t] : 0.0f;
#pragma unroll
    for (int off = 1; off < 64; off <<= 1) v += __shfl_xor(v, off);
    if (t == 0) out[0] = v / (float)N2;
}

extern "C" void kernel_launch(void* const* d_in, const int* in_sizes, int n_in,
                              void* d_out, int out_size, void* d_ws, size_t ws_size,
                              hipStream_t stream) {
    const float* zi = (const float*)d_in[0];
    const float* zj = (const float*)d_in[1];
    const int N  = in_sizes[0] / D_DIM;   // 4096
    const int N2 = 2 * N;                 // 8192

    char* w = (char*)d_ws;
    unsigned char* Z8 = (unsigned char*)w;
    size_t off = (size_t)N2 * D_DIM;                                  // 1 MB fp8
    float* posdot  = (float*)(w + off);  off += (size_t)N  * sizeof(float);
    float* selfarg = (float*)(w + off);  off += (size_t)N2 * sizeof(float);
    float* rowpart = (float*)(w + off);  off += (size_t)(2 * CS) * N2 * sizeof(float); // 1 MB
    float* bpart   = (float*)(w + off);

    prep_kernel<<<N / 4, 256, 0, stream>>>(zi, zj, Z8, posdot, selfarg, N);
    dim3 grid(N2 / BLK_ROWS, CS);
    main_kernel<<<grid, 512, 0, stream>>>(Z8, rowpart, N2);
    const int nb = N2 / 256;  // 32
    finalize1_kernel<<<nb, 256, 0, stream>>>(rowpart, selfarg, posdot, bpart, N2, N);
    finalize2_kernel<<<1, 64, 0, stream>>>(bpart, (float*)d_out, nb, N2);
}